// Round 22
// baseline (165.883 us; speedup 1.0000x reference)
//
#include <hip/hip_runtime.h>
#include <hip/hip_bf16.h>
#include <stdint.h>

typedef __bf16 bf16;
typedef __attribute__((ext_vector_type(8))) __bf16 bf16x8;
typedef __attribute__((ext_vector_type(4))) __bf16 bf16x4;
typedef __attribute__((ext_vector_type(4))) float f32x4;

typedef __attribute__((address_space(3))) char* lds_ptr;
typedef const __attribute__((address_space(1))) char* glb_ptr;

#define BZ 4
#define NN 2048
#define CC 1024

__device__ __forceinline__ void gload_lds16(const bf16* g, bf16* l) {
    __builtin_amdgcn_global_load_lds((glb_ptr)g, (lds_ptr)l, 16, 0, 0);
}

__device__ __forceinline__ void bar() {
    asm volatile("" ::: "memory");
    __builtin_amdgcn_s_barrier();
    asm volatile("" ::: "memory");
}

// ------- u[c] = sum_d Wk[c][d]*bq[d]; also zeroes rowsum+beta (16384 f32) -------
__global__ void ucomp(const float* __restrict__ Wk, const float* __restrict__ bq,
                      float* __restrict__ u, float* __restrict__ zbuf) {
    __shared__ float red[4];
    const int c = blockIdx.x, t = threadIdx.x;  // 1024 blocks x 256 thr
    int gid = blockIdx.x * 256 + t;
    if (gid < 2 * BZ * NN) zbuf[gid] = 0.f;
    float p = 0.f;
    for (int d = t; d < CC; d += 256) p += Wk[(size_t)c * CC + d] * bq[d];
#pragma unroll
    for (int off = 32; off; off >>= 1) p += __shfl_xor(p, off);
    if ((t & 63) == 0) red[t >> 6] = p;
    __syncthreads();
    if (t == 0) u[c] = red[0] + red[1] + red[2] + red[3];
}

// -------- fp32 -> bf16 convert: e, i, Wq, Wk in one dispatch (8 elems/thr);
//          i-segment also accumulates beta[row] += i[row,:]*u via wave reduce --------
__global__ void cvt4(const float* __restrict__ e, const float* __restrict__ im,
                     const float* __restrict__ wq, const float* __restrict__ wk,
                     bf16* __restrict__ oe, bf16* __restrict__ oi,
                     bf16* __restrict__ owq, bf16* __restrict__ owk,
                     const float* __restrict__ u, float* __restrict__ beta,
                     int n8, int w8) {
    int idx = blockIdx.x * blockDim.x + threadIdx.x;
    const float* src;
    bf16* dst;
    int j;
    bool isI = false;
    if (idx < n8) { src = e; dst = oe; j = idx; }
    else if (idx < 2 * n8) { src = im; dst = oi; j = idx - n8; isI = true; }
    else if (idx < 2 * n8 + w8) { src = wq; dst = owq; j = idx - 2 * n8; }
    else if (idx < 2 * n8 + 2 * w8) { src = wk; dst = owk; j = idx - 2 * n8 - w8; }
    else return;
    float4 x = ((const float4*)src)[2 * j], y = ((const float4*)src)[2 * j + 1];
    bf16x8 o;
    o[0] = (bf16)x.x; o[1] = (bf16)x.y; o[2] = (bf16)x.z; o[3] = (bf16)x.w;
    o[4] = (bf16)y.x; o[5] = (bf16)y.y; o[6] = (bf16)y.z; o[7] = (bf16)y.w;
    *(bf16x8*)(dst + 8 * (size_t)j) = o;
    if (isI) {
        // 128 threads per 1024-col row; each 64-lane wave lies in ONE row.
        int c0 = (j & 127) * 8;
        float p = x.x * u[c0] + x.y * u[c0 + 1] + x.z * u[c0 + 2] + x.w * u[c0 + 3] +
                  y.x * u[c0 + 4] + y.y * u[c0 + 5] + y.z * u[c0 + 6] + y.w * u[c0 + 7];
#pragma unroll
        for (int off = 32; off; off >>= 1) p += __shfl_xor(p, off);
        if ((threadIdx.x & 63) == 0) atomicAdd(&beta[j >> 7], p);
    }
}

// ------- Wv [C][C] f32 -> Wvt [d][c] bf16 transposed -------
__global__ void transposeW1(const float* __restrict__ W, bf16* __restrict__ Wt) {
    __shared__ bf16 t[32][33];
    int d0 = blockIdx.x * 32, c0 = blockIdx.y * 32;
    int tx = threadIdx.x, ty = threadIdx.y;  // 32x8
#pragma unroll
    for (int i = 0; i < 4; i++)
        t[ty + 8 * i][tx] = (bf16)W[(size_t)(c0 + ty + 8 * i) * CC + d0 + tx];
    __syncthreads();
#pragma unroll
    for (int i = 0; i < 4; i++)
        Wt[(size_t)(d0 + ty + 8 * i) * CC + c0 + tx] = t[tx][ty + 8 * i];
}

// ------- sum 4 f32 split-K partials -> bf16 G (4 elems/thr) -------
__global__ void sumcvt(const float* __restrict__ P, bf16* __restrict__ G, int n4) {
    int i = blockIdx.x * blockDim.x + threadIdx.x;
    if (i >= n4) return;
    const size_t S1 = (size_t)CC * CC;
    float4 a = ((const float4*)P)[i];
    float4 b = ((const float4*)(P + S1))[i];
    float4 c = ((const float4*)(P + 2 * S1))[i];
    float4 d = ((const float4*)(P + 3 * S1))[i];
    bf16x4 o;
    o[0] = (bf16)(a.x + b.x + c.x + d.x);
    o[1] = (bf16)(a.y + b.y + c.y + d.y);
    o[2] = (bf16)(a.z + b.z + c.z + d.z);
    o[3] = (bf16)(a.w + b.w + c.w + d.w);
    *(bf16x4*)(G + 4 * (size_t)i) = o;
}

// ================= shared GEMM machinery (macros) =================
#define STAGE_A(kt_, hh_)                                                          \
    do {                                                                           \
        int _kt = (kt_);                                                           \
        if (_kt < nkt) {                                                           \
            const bf16* _s = gAs + (size_t)((hh_) * (BM / 2)) * lda +              \
                             (size_t)_kt * 64;                                     \
            bf16* _d = &LA[_kt & 1][((hh_) * (BM / 2) + wid * 16) * 64];           \
            gload_lds16(_s, _d);                                                   \
            gload_lds16(_s + (size_t)8 * lda, _d + 8 * 64);                        \
        }                                                                          \
    } while (0)

#define STAGE_B(kt_, hh_)                                                          \
    do {                                                                           \
        int _kt = (kt_);                                                           \
        if (_kt < nkt) {                                                           \
            const bf16* _s = gBs + (size_t)((hh_) * (BN / 2)) * ldb +              \
                             (size_t)_kt * 64;                                     \
            bf16* _d = &LB[_kt & 1][((hh_) * (BN / 2) + wid * 16) * 64];           \
            gload_lds16(_s, _d);                                                   \
            gload_lds16(_s + (size_t)8 * ldb, _d + 8 * 64);                        \
        }                                                                          \
    } while (0)

#define LDA_FRAG(buf_, mh_, dst_)                                                \
    do {                                                                         \
        _Pragma("unroll") for (int _i = 0; _i < MI; ++_i)                        \
            _Pragma("unroll") for (int _ks = 0; _ks < 2; ++_ks)                  \
                dst_[_i][_ks] = *(const bf16x8*)&LA[buf_][                       \
                    (wm + (mh_) * (WAVE_M / 2) + _i * 16 + fr) * 64 +            \
                    (((_ks * 4 + hi) ^ lo) * 8)];                                \
    } while (0)

#define LDB_FRAG(buf_, nh_, dst_)                                                \
    do {                                                                         \
        _Pragma("unroll") for (int _j = 0; _j < 2; ++_j)                         \
            _Pragma("unroll") for (int _ks = 0; _ks < 2; ++_ks)                  \
                dst_[_j][_ks] = *(const bf16x8*)&LB[buf_][                       \
                    (wn + (nh_)*32 + _j * 16 + fr) * 64 +                        \
                    (((_ks * 4 + hi) ^ lo) * 8)];                                \
    } while (0)

#define MMQ(mh_, nh_, a_, b_)                                                    \
    do {                                                                         \
        __builtin_amdgcn_s_setprio(1);                                           \
        _Pragma("unroll") for (int _i = 0; _i < MI; ++_i)                        \
            _Pragma("unroll") for (int _j = 0; _j < 2; ++_j)                     \
                _Pragma("unroll") for (int _ks = 0; _ks < 2; ++_ks)              \
                    acc[(mh_)*MI + _i][(nh_)*2 + _j] =                           \
                        __builtin_amdgcn_mfma_f32_16x16x32_bf16(                 \
                            a_[_i][_ks], b_[_j][_ks],                            \
                            acc[(mh_)*MI + _i][(nh_)*2 + _j], 0, 0, 0);          \
        __builtin_amdgcn_s_setprio(0);                                           \
    } while (0)

#define VMW(n_) asm volatile("s_waitcnt vmcnt(" #n_ ")" ::: "memory")

// ================= BMxBN bf16 B^T GEMM (r17/r21-proven) =================
template <int TB, int BM, int BN, int EPI, bool OUT_F32>
__global__ __launch_bounds__(TB, 2) void gemm8(
    const bf16* __restrict__ A, int lda,
    const bf16* __restrict__ Bt, int ldb,
    void* __restrict__ Cout, int ldc,
    float* __restrict__ aux, long long sAux,
    const float* __restrict__ fold, long long sFold, float scale,
    long long sA, long long sB, long long sC, int nkt) {
    constexpr int WNW = (TB == 512) ? 4 : 2;    // wave-grid N dim
    constexpr int WAVE_M = BM / 2;              // per-wave M
    constexpr int MI = WAVE_M / 32;             // m-frags per half
    static_assert(BN / WNW == 64, "wave_n must be 64");
    __shared__ __align__(16) bf16 LA[2][BM * 64];
    __shared__ __align__(16) bf16 LB[2][BN * 64];

    // ---- XCD-chunked bijective swizzle (m204)
    const int nx = gridDim.x, ny = gridDim.y;
    const int nwg = nx * ny * gridDim.z;
    const int orig = blockIdx.x + nx * (blockIdx.y + ny * blockIdx.z);
    const int q = nwg >> 3, r = nwg & 7;
    const int xcd = orig & 7, land = orig >> 3;
    const int swz = (xcd < r ? xcd * (q + 1) : r * (q + 1) + (xcd - r) * q) + land;
    const int bx = swz % nx;
    const int tmp = swz / nx;
    const int by = tmp % ny, bz = tmp / ny;

    A += (size_t)bz * sA;
    Bt += (size_t)bz * sB;
    const int m0 = by * BM, n0 = bx * BN;
    const int t = threadIdx.x, wid = t >> 6, lane = t & 63;
    const int wm = (wid / WNW) * WAVE_M, wn = (wid % WNW) * 64;
    const int fr = lane & 15, hi = lane >> 4, lo = lane & 7;
    f32x4 acc[2 * MI][4] = {};

    // staging lane geometry: per gload, wave covers 8 rows x 8 chunks of 16B;
    // source chunk pre-swizzled (chunk ^= row&7), LDS dest linear.
    const int srow = lane >> 3;
    const int schunk = lo ^ srow;
    const bf16* gAs = A + (size_t)(m0 + wid * 16 + srow) * lda + schunk * 8;
    const bf16* gBs = Bt + (size_t)(n0 + wid * 16 + srow) * ldb + schunk * 8;

    bf16x8 aA[MI][2], b0[2][2], b1[2][2];
    if constexpr (TB == 256) {
        bf16x8 aB[MI][2];
        STAGE_A(0, 0); STAGE_A(0, 1); STAGE_B(0, 0); STAGE_B(0, 1);
        STAGE_B(1, 0); STAGE_A(1, 0); STAGE_B(1, 1);
        VMW(6);
        bar();
        // ---- r15-proven 2-phase schedule (128x128) ----
        for (int kt = 0; kt < nkt; ++kt) {
            const int buf = kt & 1;
            LDA_FRAG(buf, 0, aA);
            LDA_FRAG(buf, 1, aB);
            LDB_FRAG(buf, 0, b0);
            LDB_FRAG(buf, 1, b1);
            STAGE_A(kt + 1, 1);
            MMQ(0, 0, aA, b0);
            MMQ(0, 1, aA, b1);
            bar();
            STAGE_B(kt + 2, 0);
            STAGE_B(kt + 2, 1);
            STAGE_A(kt + 2, 0);
            MMQ(1, 1, aB, b1);
            MMQ(1, 0, aB, b0);
            if (kt + 2 < nkt) VMW(6);
            else VMW(0);
            bar();
        }
    } else {
        STAGE_A(0, 0); STAGE_A(0, 1); STAGE_B(0, 0); STAGE_B(0, 1);
        VMW(0);
        bar();
        // ---- r17-proven 2-phase schedule (256x256) ----
        for (int kt = 0; kt < nkt; ++kt) {
            const int buf = kt & 1;
            LDA_FRAG(buf, 0, aA);
            LDB_FRAG(buf, 0, b0);
            LDB_FRAG(buf, 1, b1);
            STAGE_A(kt + 1, 0);
            STAGE_A(kt + 1, 1);
            STAGE_B(kt + 1, 0);
            STAGE_B(kt + 1, 1);
            MMQ(0, 0, aA, b0);
            MMQ(0, 1, aA, b1);
            bar();
            LDA_FRAG(buf, 1, aA);
            MMQ(1, 1, aA, b1);
            MMQ(1, 0, aA, b0);
            VMW(0);
            bar();
        }
    }

    // epilogue: C write (C/D map: col=lane&15, row=(lane>>4)*4+reg)
    const int rq = hi * 4;
#pragma unroll
    for (int mh = 0; mh < 2; mh++)
#pragma unroll
        for (int i = 0; i < MI; i++) {
            const int row = m0 + wm + mh * (WAVE_M / 2) + i * 16 + rq;
            float rsum[4] = {0.f, 0.f, 0.f, 0.f};
            float inv[4];
            if (EPI == 4) {
#pragma unroll
                for (int rr = 0; rr < 4; rr++)
                    inv[rr] = 1.f / aux[bz * sAux + row + rr];
            }
#pragma unroll
            for (int nh = 0; nh < 2; nh++)
#pragma unroll
                for (int j = 0; j < 2; j++) {
                    int col = n0 + wn + nh * 32 + j * 16 + fr;
                    float fc = (EPI == 5) ? fold[bz * sFold + col] * scale : 0.f;
                    f32x4 v = acc[mh * MI + i][nh * 2 + j];
#pragma unroll
                    for (int rr = 0; rr < 4; rr++) {
                        float o = v[rr] * scale;
                        if (EPI == 2) o += aux[row + rr];
                        if (EPI == 5) { o = __expf(o + fc - 6.f); rsum[rr] += o; }
                        if (EPI == 4) o *= inv[rr];
                        if (OUT_F32)
                            ((float*)Cout)[(size_t)bz * sC + (size_t)(row + rr) * ldc + col] = o;
                        else
                            ((bf16*)Cout)[(size_t)bz * sC + (size_t)(row + rr) * ldc + col] = (bf16)o;
                    }
                }
            if (EPI == 5) {
#pragma unroll
                for (int rr = 0; rr < 4; rr++) {
                    float s = rsum[rr];
                    s += __shfl_xor(s, 1);
                    s += __shfl_xor(s, 2);
                    s += __shfl_xor(s, 4);
                    s += __shfl_xor(s, 8);
                    if (fr == 0) atomicAdd(&aux[bz * sAux + row + rr], s);
                }
            }
        }
}

// ========== fused T + VT dispatch (both 128x128, 2-phase, nkt=16) ==========
// grid (16, 8, 8), 1024 blocks at 2/CU: roles backfill each other's
// stragglers (each standalone dispatch was exactly one scheduling wave).
// z in [0,4): VT batch z  (A=Wvt, Bt=Ibf_z, C=VT_z, ldc=NN, row-bias bv)
// z in [4,8): T            (flat=bx+16*by -> tbx=flat&7, tby=(z-4)*16+flat>>3;
//                           A=Ebf, Bt=Gt, C=Tb, ldc=CC, no bias)
__global__ __launch_bounds__(256, 2) void gemm_tv(
    const bf16* __restrict__ Ebf, const bf16* __restrict__ Gt,
    bf16* __restrict__ Tb,
    const bf16* __restrict__ Wvt, const bf16* __restrict__ Ibf,
    bf16* __restrict__ VT, const float* __restrict__ bv) {
    constexpr int BM = 128, BN = 128, WAVE_M = 64, MI = 2, WNW = 2;
    const int nkt = CC / 64;  // 16 for both roles
    __shared__ __align__(16) bf16 LA[2][BM * 64];
    __shared__ __align__(16) bf16 LB[2][BN * 64];

    // ---- XCD-chunked bijective swizzle on the fused grid (nwg=1024, r=0)
    const int nx = gridDim.x, ny = gridDim.y;
    const int nwg = nx * ny * gridDim.z;
    const int orig = blockIdx.x + nx * (blockIdx.y + ny * blockIdx.z);
    const int q = nwg >> 3, r = nwg & 7;
    const int xcd = orig & 7, land = orig >> 3;
    const int swz = (xcd < r ? xcd * (q + 1) : r * (q + 1) + (xcd - r) * q) + land;
    const int bxF = swz % nx;
    const int tmpF = swz / nx;
    const int byF = tmpF % ny, bzF = tmpF / ny;

    // ---- block-uniform role decode
    const bf16 *A, *Bt;
    bf16* Cout;
    const float* rowBias;
    int ldc_, m0, n0;
    if (bzF < BZ) {  // VT role
        A = Wvt;
        Bt = Ibf + (size_t)bzF * NN * CC;
        Cout = VT + (size_t)bzF * CC * NN;
        ldc_ = NN;
        rowBias = bv;
        m0 = byF * BM;   // over CC (ny=8 -> 1024) ✓
        n0 = bxF * BN;   // over NN (nx=16 -> 2048) ✓
    } else {  // T role
        const int flat = bxF + 16 * byF;          // [0,128)
        A = Ebf;
        Bt = Gt;
        Cout = Tb;
        ldc_ = CC;
        rowBias = nullptr;
        m0 = ((bzF - BZ) * 16 + (flat >> 3)) * BM;  // over 8192 ✓ bijective
        n0 = (flat & 7) * BN;                       // over CC ✓
    }
    const int lda = CC, ldb = CC;

    const int t = threadIdx.x, wid = t >> 6, lane = t & 63;
    const int wm = (wid / WNW) * WAVE_M, wn = (wid % WNW) * 64;
    const int fr = lane & 15, hi = lane >> 4, lo = lane & 7;
    f32x4 acc[2 * MI][4] = {};

    const int srow = lane >> 3;
    const int schunk = lo ^ srow;
    const bf16* gAs = A + (size_t)(m0 + wid * 16 + srow) * lda + schunk * 8;
    const bf16* gBs = Bt + (size_t)(n0 + wid * 16 + srow) * ldb + schunk * 8;

    bf16x8 aA[MI][2], aB[MI][2], b0[2][2], b1[2][2];
    // prologue: tile0 fully + B0(1),A0(1),B1(1) half-stages
    STAGE_A(0, 0); STAGE_A(0, 1); STAGE_B(0, 0); STAGE_B(0, 1);
    STAGE_B(1, 0); STAGE_A(1, 0); STAGE_B(1, 1);
    VMW(6);
    bar();
    // ---- r15-proven 2-phase schedule (128x128) ----
    for (int kt = 0; kt < nkt; ++kt) {
        const int buf = kt & 1;
        LDA_FRAG(buf, 0, aA);
        LDA_FRAG(buf, 1, aB);
        LDB_FRAG(buf, 0, b0);
        LDB_FRAG(buf, 1, b1);
        STAGE_A(kt + 1, 1);
        MMQ(0, 0, aA, b0);
        MMQ(0, 1, aA, b1);
        bar();
        STAGE_B(kt + 2, 0);
        STAGE_B(kt + 2, 1);
        STAGE_A(kt + 2, 0);
        MMQ(1, 1, aB, b1);
        MMQ(1, 0, aB, b0);
        if (kt + 2 < nkt) VMW(6);
        else VMW(0);
        bar();
    }

    // epilogue: C write (C/D map: col=lane&15, row=(lane>>4)*4+reg)
    const int rq = hi * 4;
#pragma unroll
    for (int mh = 0; mh < 2; mh++)
#pragma unroll
        for (int i = 0; i < MI; i++) {
            const int row = m0 + wm + mh * (WAVE_M / 2) + i * 16 + rq;
#pragma unroll
            for (int nh = 0; nh < 2; nh++)
#pragma unroll
                for (int j = 0; j < 2; j++) {
                    int col = n0 + wn + nh * 32 + j * 16 + fr;
                    f32x4 v = acc[mh * MI + i][nh * 2 + j];
#pragma unroll
                    for (int rr = 0; rr < 4; rr++) {
                        float o = v[rr];
                        if (rowBias) o += rowBias[row + rr];
                        Cout[(size_t)(row + rr) * ldc_ + col] = (bf16)o;
                    }
                }
        }
}

extern "C" void kernel_launch(void* const* d_in, const int* in_sizes, int n_in,
                              void* d_out, int out_size, void* d_ws, size_t ws_size,
                              hipStream_t stream) {
    const float* event_f = (const float*)d_in[0];
    const float* img_f   = (const float*)d_in[1];
    const float* Wq = (const float*)d_in[2];
    const float* bq = (const float*)d_in[3];
    const float* Wk = (const float*)d_in[4];
    const float* bk = (const float*)d_in[5];  // shift-invariant: cancels in softmax
    const float* Wv = (const float*)d_in[6];
    const float* bv = (const float*)d_in[7];
    float* out = (float*)d_out;
    (void)bk;

    bf16* ws = (bf16*)d_ws;
    const size_t MC = (size_t)BZ * NN * CC;   // 8388608
    const size_t CCsq = (size_t)CC * CC;      // 1048576
    // layout (bf16 elements)
    bf16* Ebf  = ws;                          // MC   (dead after T-GEMM)
    bf16* Ibf  = ws + MC;                     // MC   (live through QK)
    size_t off = 2 * MC;
    bf16* Wqbf = ws + off; off += CCsq;       // flat bf16 (no transpose)
    bf16* Wkbf = ws + off; off += CCsq;
    bf16* Wvt  = ws + off; off += CCsq;       // transposed for VT-GEMM
    bf16* Gt   = ws + off; off += CCsq;       // Gt[c'][c] = G[c,c'] bf16
    bf16* Tb   = ws + off; off += MC;         // T = e*G  [8192][1024]
    bf16* VT   = ws + off; off += MC;         // [B][1024][2048]
    bf16* S    = ws + off; off += 2 * MC;     // exp-scores [B][2048][2048]
    float* Gpart = (float*)S;                 // 4 x CCsq f32 split-K partials
                                              // (aliases S; dead before QK writes S)
    float* fbase  = (float*)(ws + off);
    float* rowsum = fbase;                    // 8192
    float* beta   = fbase + BZ * NN;          // 8192
    float* u      = fbase + 2 * BZ * NN;      // 1024

    // 1. u = Wk * bq; also zeroes rowsum+beta (no separate memset)
    ucomp<<<dim3(CC), dim3(256), 0, stream>>>(Wk, bq, u, rowsum);
    // 2. convert e, i, Wq, Wk to bf16; fuse beta = i*u accumulation
    {
        int n8 = (int)(MC / 8), w8 = (int)(CCsq / 8);
        int tot = 2 * n8 + 2 * w8;
        cvt4<<<dim3((tot + 255) / 256), dim3(256), 0, stream>>>(
            event_f, img_f, Wq, Wk, Ebf, Ibf, Wqbf, Wkbf, u, beta, n8, w8);
    }
    // 3. transpose Wv only
    transposeW1<<<dim3(CC / 32, CC / 32), dim3(32, 8), 0, stream>>>(Wv, Wvt);
    // 4. split-K G partials: Gpart[z][c'][c] = sum_{d in chunk z} Wk[c',d]*Wq[c,d]
    gemm8<256, 128, 128, 0, true><<<dim3(8, 8, 4), dim3(256), 0, stream>>>(
        Wkbf, CC, Wqbf, CC, Gpart, CC, nullptr, 0, nullptr, 0, 1.f,
        256, 256, (long long)CCsq, 4);
    // 5. Gt = sum of 4 partials, cast bf16
    sumcvt<<<dim3((CCsq / 4 + 255) / 256), dim3(256), 0, stream>>>(
        Gpart, Gt, (int)(CCsq / 4));
    // 6+7 fused. T = e @ Gt^T  and  VT = Wv^T @ img^T + bv in ONE dispatch
    //   (1024 blocks; roles backfill each other's dispatch stragglers)
    gemm_tv<<<dim3(16, 8, 8), dim3(256), 0, stream>>>(
        Ebf, Gt, Tb, Wvt, Ibf, VT, bv);
    // 8. S = exp((T@i^T + beta_col)/32 - 6) + row-sum atomics -- 256x256
    //    2-phase path (r17-proven)
    gemm8<512, 256, 256, 5, false><<<dim3(NN / 256, NN / 256, BZ), dim3(512), 0, stream>>>(
        Tb, CC, Ibf, CC, S, NN, rowsum, NN, beta, NN, 1.f / 32.f,
        (long long)NN * CC, (long long)NN * CC, (long long)NN * NN, CC / 64);
    // 9. out = (S @ V) / rowsum  (per batch 2048x1024, K=2048) -> fp32
    gemm8<256, 128, 128, 4, true><<<dim3(CC / 128, NN / 128, BZ), dim3(256), 0, stream>>>(
        S, NN, VT, NN, out, CC, rowsum, NN, nullptr, 0, 1.f,
        (long long)NN * NN, (long long)CC * NN, (long long)NN * CC, NN / 64);
}

// Round 23
// 159.660 us; speedup vs baseline: 1.0390x; 1.0390x over previous
//
#include <hip/hip_runtime.h>
#include <hip/hip_bf16.h>
#include <stdint.h>

typedef __bf16 bf16;
typedef __attribute__((ext_vector_type(8))) __bf16 bf16x8;
typedef __attribute__((ext_vector_type(4))) __bf16 bf16x4;
typedef __attribute__((ext_vector_type(4))) float f32x4;

typedef __attribute__((address_space(3))) char* lds_ptr;
typedef const __attribute__((address_space(1))) char* glb_ptr;

#define BZ 4
#define NN 2048
#define CC 1024

__device__ __forceinline__ void gload_lds16(const bf16* g, bf16* l) {
    __builtin_amdgcn_global_load_lds((glb_ptr)g, (lds_ptr)l, 16, 0, 0);
}

__device__ __forceinline__ void bar() {
    asm volatile("" ::: "memory");
    __builtin_amdgcn_s_barrier();
    asm volatile("" ::: "memory");
}

// ------- u[c] = sum_d Wk[c][d]*bq[d]; also zeroes rowsum+beta (16384 f32) -------
__global__ void ucomp(const float* __restrict__ Wk, const float* __restrict__ bq,
                      float* __restrict__ u, float* __restrict__ zbuf) {
    __shared__ float red[4];
    const int c = blockIdx.x, t = threadIdx.x;  // 1024 blocks x 256 thr
    int gid = blockIdx.x * 256 + t;
    if (gid < 2 * BZ * NN) zbuf[gid] = 0.f;
    float p = 0.f;
    for (int d = t; d < CC; d += 256) p += Wk[(size_t)c * CC + d] * bq[d];
#pragma unroll
    for (int off = 32; off; off >>= 1) p += __shfl_xor(p, off);
    if ((t & 63) == 0) red[t >> 6] = p;
    __syncthreads();
    if (t == 0) u[c] = red[0] + red[1] + red[2] + red[3];
}

// -------- fp32 -> bf16 convert: e, i, Wq, Wk in one dispatch (8 elems/thr);
//          i-segment also accumulates beta[row] += i[row,:]*u via wave reduce --------
__global__ void cvt4(const float* __restrict__ e, const float* __restrict__ im,
                     const float* __restrict__ wq, const float* __restrict__ wk,
                     bf16* __restrict__ oe, bf16* __restrict__ oi,
                     bf16* __restrict__ owq, bf16* __restrict__ owk,
                     const float* __restrict__ u, float* __restrict__ beta,
                     int n8, int w8) {
    int idx = blockIdx.x * blockDim.x + threadIdx.x;
    const float* src;
    bf16* dst;
    int j;
    bool isI = false;
    if (idx < n8) { src = e; dst = oe; j = idx; }
    else if (idx < 2 * n8) { src = im; dst = oi; j = idx - n8; isI = true; }
    else if (idx < 2 * n8 + w8) { src = wq; dst = owq; j = idx - 2 * n8; }
    else if (idx < 2 * n8 + 2 * w8) { src = wk; dst = owk; j = idx - 2 * n8 - w8; }
    else return;
    float4 x = ((const float4*)src)[2 * j], y = ((const float4*)src)[2 * j + 1];
    bf16x8 o;
    o[0] = (bf16)x.x; o[1] = (bf16)x.y; o[2] = (bf16)x.z; o[3] = (bf16)x.w;
    o[4] = (bf16)y.x; o[5] = (bf16)y.y; o[6] = (bf16)y.z; o[7] = (bf16)y.w;
    *(bf16x8*)(dst + 8 * (size_t)j) = o;
    if (isI) {
        // 128 threads per 1024-col row; each 64-lane wave lies in ONE row.
        int c0 = (j & 127) * 8;
        float p = x.x * u[c0] + x.y * u[c0 + 1] + x.z * u[c0 + 2] + x.w * u[c0 + 3] +
                  y.x * u[c0 + 4] + y.y * u[c0 + 5] + y.z * u[c0 + 6] + y.w * u[c0 + 7];
#pragma unroll
        for (int off = 32; off; off >>= 1) p += __shfl_xor(p, off);
        if ((threadIdx.x & 63) == 0) atomicAdd(&beta[j >> 7], p);
    }
}

// ------- Wv [C][C] f32 -> Wvt [d][c] bf16 transposed -------
__global__ void transposeW1(const float* __restrict__ W, bf16* __restrict__ Wt) {
    __shared__ bf16 t[32][33];
    int d0 = blockIdx.x * 32, c0 = blockIdx.y * 32;
    int tx = threadIdx.x, ty = threadIdx.y;  // 32x8
#pragma unroll
    for (int i = 0; i < 4; i++)
        t[ty + 8 * i][tx] = (bf16)W[(size_t)(c0 + ty + 8 * i) * CC + d0 + tx];
    __syncthreads();
#pragma unroll
    for (int i = 0; i < 4; i++)
        Wt[(size_t)(d0 + ty + 8 * i) * CC + c0 + tx] = t[tx][ty + 8 * i];
}

// ------- sum 4 f32 split-K partials -> bf16 G (4 elems/thr) -------
__global__ void sumcvt(const float* __restrict__ P, bf16* __restrict__ G, int n4) {
    int i = blockIdx.x * blockDim.x + threadIdx.x;
    if (i >= n4) return;
    const size_t S1 = (size_t)CC * CC;
    float4 a = ((const float4*)P)[i];
    float4 b = ((const float4*)(P + S1))[i];
    float4 c = ((const float4*)(P + 2 * S1))[i];
    float4 d = ((const float4*)(P + 3 * S1))[i];
    bf16x4 o;
    o[0] = (bf16)(a.x + b.x + c.x + d.x);
    o[1] = (bf16)(a.y + b.y + c.y + d.y);
    o[2] = (bf16)(a.z + b.z + c.z + d.z);
    o[3] = (bf16)(a.w + b.w + c.w + d.w);
    *(bf16x4*)(G + 4 * (size_t)i) = o;
}

// ================= BMxBN bf16 B^T GEMM =================
// C[m][n] = scale * sum_k A[m][k]*Bt[n][k]  (+ epilogue op)
// EPI: 0 none; 2 row-bias aux[row]; 4 row-scale C=s/aux[bz*sAux+row];
//      5 softmax-numerator with col-shift: C = exp(s*scale + fold*scale - 6)
//        + f32 row-sum atomics into aux.
// TB=256, 128x128 (r15-proven 2-phase): Pa reads all 16 frags + stages
//   A1(kt+1); Pb pure-MFMA + stages B0/B1(kt+2)+A0(kt+2); vmcnt(6)/tile.
// TB=512, 256x256 (r17-proven 2-phase): Pa reads A-mh0 + ALL B + stages all
//   of kt+1 -> nbuf; Pb reads A-mh1 + MMQ(1,*) + vmcnt(0). Structurally no
//   same-phase DMA/read overlap (stages target nbuf, reads hit buf).

#define STAGE_A(kt_, hh_)                                                          \
    do {                                                                           \
        int _kt = (kt_);                                                           \
        if (_kt < nkt) {                                                           \
            const bf16* _s = gAs + (size_t)((hh_) * (BM / 2)) * lda +              \
                             (size_t)_kt * 64;                                     \
            bf16* _d = &LA[_kt & 1][((hh_) * (BM / 2) + wid * 16) * 64];           \
            gload_lds16(_s, _d);                                                   \
            gload_lds16(_s + (size_t)8 * lda, _d + 8 * 64);                        \
        }                                                                          \
    } while (0)

#define STAGE_B(kt_, hh_)                                                          \
    do {                                                                           \
        int _kt = (kt_);                                                           \
        if (_kt < nkt) {                                                           \
            const bf16* _s = gBs + (size_t)((hh_) * (BN / 2)) * ldb +              \
                             (size_t)_kt * 64;                                     \
            bf16* _d = &LB[_kt & 1][((hh_) * (BN / 2) + wid * 16) * 64];           \
            gload_lds16(_s, _d);                                                   \
            gload_lds16(_s + (size_t)8 * ldb, _d + 8 * 64);                        \
        }                                                                          \
    } while (0)

#define LDA_FRAG(buf_, mh_, dst_)                                                \
    do {                                                                         \
        _Pragma("unroll") for (int _i = 0; _i < MI; ++_i)                        \
            _Pragma("unroll") for (int _ks = 0; _ks < 2; ++_ks)                  \
                dst_[_i][_ks] = *(const bf16x8*)&LA[buf_][                       \
                    (wm + (mh_) * (WAVE_M / 2) + _i * 16 + fr) * 64 +            \
                    (((_ks * 4 + hi) ^ lo) * 8)];                                \
    } while (0)

#define LDB_FRAG(buf_, nh_, dst_)                                                \
    do {                                                                         \
        _Pragma("unroll") for (int _j = 0; _j < 2; ++_j)                         \
            _Pragma("unroll") for (int _ks = 0; _ks < 2; ++_ks)                  \
                dst_[_j][_ks] = *(const bf16x8*)&LB[buf_][                       \
                    (wn + (nh_)*32 + _j * 16 + fr) * 64 +                        \
                    (((_ks * 4 + hi) ^ lo) * 8)];                                \
    } while (0)

#define MMQ(mh_, nh_, a_, b_)                                                    \
    do {                                                                         \
        __builtin_amdgcn_s_setprio(1);                                           \
        _Pragma("unroll") for (int _i = 0; _i < MI; ++_i)                        \
            _Pragma("unroll") for (int _j = 0; _j < 2; ++_j)                     \
                _Pragma("unroll") for (int _ks = 0; _ks < 2; ++_ks)              \
                    acc[(mh_)*MI + _i][(nh_)*2 + _j] =                           \
                        __builtin_amdgcn_mfma_f32_16x16x32_bf16(                 \
                            a_[_i][_ks], b_[_j][_ks],                            \
                            acc[(mh_)*MI + _i][(nh_)*2 + _j], 0, 0, 0);          \
        __builtin_amdgcn_s_setprio(0);                                           \
    } while (0)

#define VMW(n_) asm volatile("s_waitcnt vmcnt(" #n_ ")" ::: "memory")

template <int TB, int BM, int BN, int EPI, bool OUT_F32>
__global__ __launch_bounds__(TB, 2) void gemm8(
    const bf16* __restrict__ A, int lda,
    const bf16* __restrict__ Bt, int ldb,
    void* __restrict__ Cout, int ldc,
    float* __restrict__ aux, long long sAux,
    const float* __restrict__ fold, long long sFold, float scale,
    long long sA, long long sB, long long sC, int nkt) {
    constexpr int WNW = (TB == 512) ? 4 : 2;    // wave-grid N dim
    constexpr int WAVE_M = BM / 2;              // per-wave M
    constexpr int MI = WAVE_M / 32;             // m-frags per half
    static_assert(BN / WNW == 64, "wave_n must be 64");
    __shared__ __align__(16) bf16 LA[2][BM * 64];
    __shared__ __align__(16) bf16 LB[2][BN * 64];

    // ---- XCD-chunked bijective swizzle (m204)
    const int nx = gridDim.x, ny = gridDim.y;
    const int nwg = nx * ny * gridDim.z;
    const int orig = blockIdx.x + nx * (blockIdx.y + ny * blockIdx.z);
    const int q = nwg >> 3, r = nwg & 7;
    const int xcd = orig & 7, land = orig >> 3;
    const int swz = (xcd < r ? xcd * (q + 1) : r * (q + 1) + (xcd - r) * q) + land;
    const int bx = swz % nx;
    const int tmp = swz / nx;
    const int by = tmp % ny, bz = tmp / ny;

    A += (size_t)bz * sA;
    Bt += (size_t)bz * sB;
    const int m0 = by * BM, n0 = bx * BN;
    const int t = threadIdx.x, wid = t >> 6, lane = t & 63;
    const int wm = (wid / WNW) * WAVE_M, wn = (wid % WNW) * 64;
    const int fr = lane & 15, hi = lane >> 4, lo = lane & 7;
    f32x4 acc[2 * MI][4] = {};

    // staging lane geometry: per gload, wave covers 8 rows x 8 chunks of 16B;
    // source chunk pre-swizzled (chunk ^= row&7), LDS dest linear.
    const int srow = lane >> 3;
    const int schunk = lo ^ srow;
    const bf16* gAs = A + (size_t)(m0 + wid * 16 + srow) * lda + schunk * 8;
    const bf16* gBs = Bt + (size_t)(n0 + wid * 16 + srow) * ldb + schunk * 8;

    bf16x8 aA[MI][2], b0[2][2], b1[2][2];
    if constexpr (TB == 256) {
        bf16x8 aB[MI][2];
        // prologue: tile0 fully + B0(1),A0(1),B1(1) half-stages
        STAGE_A(0, 0); STAGE_A(0, 1); STAGE_B(0, 0); STAGE_B(0, 1);
        STAGE_B(1, 0); STAGE_A(1, 0); STAGE_B(1, 1);
        VMW(6);  // tile0 landed, 3 half-stages (6 loads) in flight
        bar();
        // ---- r15-proven 2-phase schedule (128x128) ----
        for (int kt = 0; kt < nkt; ++kt) {
            const int buf = kt & 1;
            // Pa: read ALL frags of tile kt; stage A1(kt+1) -> LA[nbuf] rows 64-127
            LDA_FRAG(buf, 0, aA);
            LDA_FRAG(buf, 1, aB);
            LDB_FRAG(buf, 0, b0);
            LDB_FRAG(buf, 1, b1);
            STAGE_A(kt + 1, 1);
            MMQ(0, 0, aA, b0);
            MMQ(0, 1, aA, b1);
            bar();
            // Pb: pure MFMA; stage B0/B1(kt+2)->LB[buf], A0(kt+2)->LA[buf] rows0-63
            STAGE_B(kt + 2, 0);
            STAGE_B(kt + 2, 1);
            STAGE_A(kt + 2, 0);
            MMQ(1, 1, aB, b1);
            MMQ(1, 0, aB, b0);
            if (kt + 2 < nkt) VMW(6);  // drain tile kt+1; keep B(kt+2)x4+A0(kt+2)x2
            else VMW(0);
            bar();
        }
    } else {
        // prologue: tile0 only (8 loads), full drain
        STAGE_A(0, 0); STAGE_A(0, 1); STAGE_B(0, 0); STAGE_B(0, 1);
        VMW(0);
        bar();
        // ---- r17-proven 2-phase schedule (256x256) ----
        for (int kt = 0; kt < nkt; ++kt) {
            const int buf = kt & 1;
            // Pa: read A-mh0 + ALL B of tile kt; stage ALL of tile kt+1 -> nbuf
            LDA_FRAG(buf, 0, aA);
            LDB_FRAG(buf, 0, b0);
            LDB_FRAG(buf, 1, b1);
            STAGE_A(kt + 1, 0);
            STAGE_A(kt + 1, 1);
            STAGE_B(kt + 1, 0);
            STAGE_B(kt + 1, 1);
            MMQ(0, 0, aA, b0);
            MMQ(0, 1, aA, b1);
            bar();
            // Pb: read A-mh1 (reuse aA regs); pure MFMA; drain tile kt+1
            LDA_FRAG(buf, 1, aA);
            MMQ(1, 1, aA, b1);
            MMQ(1, 0, aA, b0);
            VMW(0);
            bar();
        }
    }

    // epilogue: C write (C/D map: col=lane&15, row=(lane>>4)*4+reg)
    const int rq = hi * 4;
#pragma unroll
    for (int mh = 0; mh < 2; mh++)
#pragma unroll
        for (int i = 0; i < MI; i++) {
            const int row = m0 + wm + mh * (WAVE_M / 2) + i * 16 + rq;
            float rsum[4] = {0.f, 0.f, 0.f, 0.f};
            float inv[4];
            if (EPI == 4) {
#pragma unroll
                for (int rr = 0; rr < 4; rr++)
                    inv[rr] = 1.f / aux[bz * sAux + row + rr];
            }
#pragma unroll
            for (int nh = 0; nh < 2; nh++)
#pragma unroll
                for (int j = 0; j < 2; j++) {
                    int col = n0 + wn + nh * 32 + j * 16 + fr;
                    float fc = (EPI == 5) ? fold[bz * sFold + col] * scale : 0.f;
                    f32x4 v = acc[mh * MI + i][nh * 2 + j];
#pragma unroll
                    for (int rr = 0; rr < 4; rr++) {
                        float o = v[rr] * scale;
                        if (EPI == 2) o += aux[row + rr];
                        if (EPI == 5) { o = __expf(o + fc - 6.f); rsum[rr] += o; }
                        if (EPI == 4) o *= inv[rr];
                        if (OUT_F32)
                            ((float*)Cout)[(size_t)bz * sC + (size_t)(row + rr) * ldc + col] = o;
                        else
                            ((bf16*)Cout)[(size_t)bz * sC + (size_t)(row + rr) * ldc + col] = (bf16)o;
                    }
                }
            if (EPI == 5) {
                // reduce the partial over the 16 fr-lanes, one f32 atomic/row/wave
#pragma unroll
                for (int rr = 0; rr < 4; rr++) {
                    float s = rsum[rr];
                    s += __shfl_xor(s, 1);
                    s += __shfl_xor(s, 2);
                    s += __shfl_xor(s, 4);
                    s += __shfl_xor(s, 8);
                    if (fr == 0) atomicAdd(&aux[bz * sAux + row + rr], s);
                }
            }
        }
}

extern "C" void kernel_launch(void* const* d_in, const int* in_sizes, int n_in,
                              void* d_out, int out_size, void* d_ws, size_t ws_size,
                              hipStream_t stream) {
    const float* event_f = (const float*)d_in[0];
    const float* img_f   = (const float*)d_in[1];
    const float* Wq = (const float*)d_in[2];
    const float* bq = (const float*)d_in[3];
    const float* Wk = (const float*)d_in[4];
    const float* bk = (const float*)d_in[5];  // shift-invariant: cancels in softmax
    const float* Wv = (const float*)d_in[6];
    const float* bv = (const float*)d_in[7];
    float* out = (float*)d_out;
    (void)bk;

    bf16* ws = (bf16*)d_ws;
    const size_t MC = (size_t)BZ * NN * CC;   // 8388608
    const size_t CCsq = (size_t)CC * CC;      // 1048576
    // layout (bf16 elements)
    bf16* Ebf  = ws;                          // MC   (dead after T-GEMM)
    bf16* Ibf  = ws + MC;                     // MC   (live through QK)
    size_t off = 2 * MC;
    bf16* Wqbf = ws + off; off += CCsq;       // flat bf16 (no transpose)
    bf16* Wkbf = ws + off; off += CCsq;
    bf16* Wvt  = ws + off; off += CCsq;       // transposed for VT-GEMM
    bf16* Gt   = ws + off; off += CCsq;       // Gt[c'][c] = G[c,c'] bf16
    bf16* Tb   = ws + off; off += MC;         // T = e*G  [8192][1024]
    bf16* VT   = ws + off; off += MC;         // [B][1024][2048]
    bf16* S    = ws + off; off += 2 * MC;     // exp-scores [B][2048][2048]
    float* Gpart = (float*)S;                 // 4 x CCsq f32 split-K partials
                                              // (aliases S; dead before QK writes S)
    float* fbase  = (float*)(ws + off);
    float* rowsum = fbase;                    // 8192
    float* beta   = fbase + BZ * NN;          // 8192
    float* u      = fbase + 2 * BZ * NN;      // 1024

    // 1. u = Wk * bq; also zeroes rowsum+beta (no separate memset)
    ucomp<<<dim3(CC), dim3(256), 0, stream>>>(Wk, bq, u, rowsum);
    // 2. convert e, i, Wq, Wk to bf16; fuse beta = i*u accumulation
    {
        int n8 = (int)(MC / 8), w8 = (int)(CCsq / 8);
        int tot = 2 * n8 + 2 * w8;
        cvt4<<<dim3((tot + 255) / 256), dim3(256), 0, stream>>>(
            event_f, img_f, Wq, Wk, Ebf, Ibf, Wqbf, Wkbf, u, beta, n8, w8);
    }
    // 3. transpose Wv only
    transposeW1<<<dim3(CC / 32, CC / 32), dim3(32, 8), 0, stream>>>(Wv, Wvt);
    // 4. split-K G partials: Gpart[z][c'][c] = sum_{d in chunk z} Wk[c',d]*Wq[c,d]
    gemm8<256, 128, 128, 0, true><<<dim3(8, 8, 4), dim3(256), 0, stream>>>(
        Wkbf, CC, Wqbf, CC, Gpart, CC, nullptr, 0, nullptr, 0, 1.f,
        256, 256, (long long)CCsq, 4);
    // 5. Gt = sum of 4 partials, cast bf16
    sumcvt<<<dim3((CCsq / 4 + 255) / 256), dim3(256), 0, stream>>>(
        Gpart, Gt, (int)(CCsq / 4));
    // 6. T = e @ Gt^T  (M=8192, N=1024, K=1024)
    gemm8<256, 128, 128, 0, false><<<dim3(CC / 128, (BZ * NN) / 128, 1), dim3(256), 0, stream>>>(
        Ebf, CC, Gt, CC, Tb, CC, nullptr, 0, nullptr, 0, 1.f, 0, 0, 0, CC / 64);
    // 7. VT = Wv^T @ img^T + bv (row-bias): per batch M=1024, N=2048, K=1024
    gemm8<256, 128, 128, 2, false><<<dim3(NN / 128, CC / 128, BZ), dim3(256), 0, stream>>>(
        Wvt, CC, Ibf, CC, VT, NN, (float*)bv, 0, nullptr, 0, 1.f,
        0, (long long)NN * CC, (long long)CC * NN, CC / 64);
    // 8. S = exp((T@i^T + beta_col)/32 - 6) + row-sum atomics -- 256x256
    //    2-phase path (r17-proven)
    gemm8<512, 256, 256, 5, false><<<dim3(NN / 256, NN / 256, BZ), dim3(512), 0, stream>>>(
        Tb, CC, Ibf, CC, S, NN, rowsum, NN, beta, NN, 1.f / 32.f,
        (long long)NN * CC, (long long)NN * CC, (long long)NN * NN, CC / 64);
    // 9. out = (S @ V) / rowsum  (per batch 2048x1024, K=2048) -> fp32
    gemm8<256, 128, 128, 4, true><<<dim3(CC / 128, NN / 128, BZ), dim3(256), 0, stream>>>(
        S, NN, VT, NN, out, CC, rowsum, NN, nullptr, 0, 1.f,
        (long long)NN * NN, (long long)CC * NN, (long long)NN * CC, NN / 64);
}